// Round 11
// baseline (59.613 us; speedup 1.0000x reference)
//
#include <hip/hip_runtime.h>
#include <math.h>

// N=100000, D=64, B=4096, W=10, L=8, M=128, T=64
constexpr int D_ = 64;
constexpr int B_ = 4096;
constexpr int W_ = 10;
constexpr int L_ = 8;
constexpr int M_ = 128;
constexpr int T_ = 64;
constexpr int NWALK = B_ * W_;   // 40960 walkers
constexpr int K_ = 16;           // lanes per walker (R10 used 8)

// R10 structure (53.3us, verified) widened to K=16 lanes/walker to saturate
// CU residency (10240 waves, 2560 blocks = 10/CU vs the 8-block cap -> full
// occupancy + tail backfill). Numerical contract unchanged:
//  - S (softmax-sum) and C (CDF) folds keep the EXACT global element order:
//    16-hop relay, lane r adds elements 4r..4r+3 after receiving the exact
//    prefix from lane r-1 via dpp row_shr:1 (rows are 16 lanes -> handoff
//    stays in-group; hop-0 leakage consumes only zeros). Bit-identical
//    sampling decisions.
//  - A/B restart-logit dots: lane-local chains + 4-stage commutative
//    butterfly (xor1/2 dpp quad_perm, xor4/8 ds_swizzle). Reordered vs the
//    reference einsum — same accepted-risk class as R9/R10 (~0.01 expected
//    flips, passed twice).
//  - fast cos (v_cos(fract(x/2pi))), in-register selection, load-up-front:
//    identical to R10.
__device__ __forceinline__ float dpp_shr1(float x) {
    int xi = __builtin_amdgcn_update_dpp(0, __float_as_int(x), 0x111, 0xF, 0xF, true);
    return __int_as_float(xi);
}
template <int CTRL>
__device__ __forceinline__ float dpp_f(float x) {   // quad_perm lane permute
    return __int_as_float(__builtin_amdgcn_update_dpp(0, __float_as_int(x), CTRL, 0xF, 0xF, true));
}
template <int CTRL>
__device__ __forceinline__ int dpp_i(int x) {
    return __builtin_amdgcn_update_dpp(0, x, CTRL, 0xF, 0xF, true);
}
template <int PAT>
__device__ __forceinline__ float swz_f(float x) {
    return __int_as_float(__builtin_amdgcn_ds_swizzle(__float_as_int(x), PAT));
}
template <int PAT>
__device__ __forceinline__ int swz_i(int x) {
    return __builtin_amdgcn_ds_swizzle(x, PAT);
}
constexpr int XOR1 = 0xB1;       // quad_perm [1,0,3,2]
constexpr int XOR2 = 0x4E;       // quad_perm [2,3,0,1]
constexpr int SWZ_XOR4  = 0x101F;   // BitMode xor lane^4
constexpr int SWZ_XOR8  = 0x201F;   // BitMode xor lane^8
constexpr int SWZ_BC15  = 0x01F0;   // new = (lane & 0x10) | 0xF : bcast lane 15/group
constexpr float INV2PI = 0.15915494309189535f;

__global__ __launch_bounds__(256) void walk_kernel(
    const int*   __restrict__ nbr_ids,      // [N,D]
    const float* __restrict__ nbr_time,     // [N,D]
    const int*   __restrict__ nbr_cnt,      // [N]
    const int*   __restrict__ start_nodes,  // [B]
    const float* __restrict__ start_times,  // [B]
    const float* __restrict__ mem,          // [N,M]
    const float* __restrict__ time_w,       // [T]
    const float* __restrict__ time_b,       // [T]
    const float* __restrict__ restart_w,    // [M+T]
    const float* __restrict__ restart_b,    // [1]
    const float* __restrict__ rand_restart, // [L,B,W]
    const float* __restrict__ rand_neighbor,// [L,B,W]
    float* __restrict__ out_nodes,          // [B,W,L+1] (as f32)
    float* __restrict__ out_times,          // [B,W,L+1]
    float* __restrict__ out_probs)          // [B,W,L]
{
    const int tid = blockIdx.x * blockDim.x + threadIdx.x;
    const int gid = tid >> 4;          // walker id
    const int r   = tid & 15;          // lane-in-group
    if (gid >= NWALK) return;
    const int b = gid / W_;

    const int   sn = start_nodes[b];
    const float st = start_times[b];
    int   cur_n = sn;
    float cur_t = st;

    float* __restrict__ on = out_nodes + (size_t)gid * (L_ + 1);
    float* __restrict__ ot = out_times + (size_t)gid * (L_ + 1);
    float* __restrict__ op = out_probs + (size_t)gid * L_;
    if (r == 0) { on[0] = (float)sn; ot[0] = st; }

    const float rb = restart_b[0];

    // loop-invariant chunks (lane r owns mem elems 8r.., time elems 4r..)
    float wv[8];
    {
        const float4* p = reinterpret_cast<const float4*>(restart_w) + r * 2;
        float4 v0 = p[0], v1 = p[1];
        *(float4*)&wv[0] = v0; *(float4*)&wv[4] = v1;
    }
    float tw[4], tb[4], rw2[4];
    {
        *(float4*)&tw[0]  = reinterpret_cast<const float4*>(time_w)[r];
        *(float4*)&tb[0]  = reinterpret_cast<const float4*>(time_b)[r];
        *(float4*)&rw2[0] = reinterpret_cast<const float4*>(restart_w + M_)[r];
    }

    for (int l = 0; l < L_; ++l) {
        // ---------- all step loads issue up-front ----------
        const float r_re = rand_restart [(size_t)l * NWALK + gid];
        const float r_nb = rand_neighbor[(size_t)l * NWALK + gid];
        const float* __restrict__ mrow    = mem      + (size_t)cur_n * M_;
        const float* __restrict__ nts_row = nbr_time + (size_t)cur_n * D_;
        const int*   __restrict__ ids_row = nbr_ids  + (size_t)cur_n * D_;
        float mv[8];
        {
            const float4* p = reinterpret_cast<const float4*>(mrow) + r * 2;
            float4 v0 = p[0], v1 = p[1];
            *(float4*)&mv[0] = v0; *(float4*)&mv[4] = v1;
        }
        float tv[4];
        *(float4*)&tv[0] = reinterpret_cast<const float4*>(nts_row)[r];
        int iv[4];
        *(int4*)&iv[0] = reinterpret_cast<const int4*>(ids_row)[r];
        const int cnt = nbr_cnt[cur_n];

        // ---------- fast time-encoder terms (restart side only) ----------
        float cosv[4];
        #pragma unroll
        for (int i = 0; i < 4; ++i) {
            const float x = cur_t * tw[i] + tb[i];
            cosv[i] = __builtin_amdgcn_cosf(__builtin_amdgcn_fractf(x * INV2PI));
        }

        float e[4];
        float lmx = -1e9f;
        #pragma unroll
        for (int i = 0; i < 4; ++i) {
            const float tj = tv[i];
            const bool  v  = (tj < cur_t) && ((4 * r + i) < cnt);
            const float s  = v ? (tj - cur_t) / 0.1f : -1e9f;   // true division
            e[i] = s;
            lmx = fmaxf(lmx, s);
        }
        lmx = fmaxf(lmx, dpp_f<XOR1>(lmx));      // xor 1 (exact permute)
        lmx = fmaxf(lmx, dpp_f<XOR2>(lmx));      // xor 2
        lmx = fmaxf(lmx, swz_f<SWZ_XOR4>(lmx));  // xor 4
        lmx = fmaxf(lmx, swz_f<SWZ_XOR8>(lmx));  // xor 8
        const bool hv = (lmx != -1e9f);

        #pragma unroll
        for (int i = 0; i < 4; ++i) e[i] = expf(e[i] - lmx);   // EXACT (cdf path)

        // ---------- restart logit: full-lane TREE reductions ----------
        float tA = 0.f;
        #pragma unroll
        for (int i = 0; i < 8; ++i) tA += mv[i] * wv[i];   // lane-local fmac chain
        tA += dpp_f<XOR1>(tA);
        tA += dpp_f<XOR2>(tA);
        tA += swz_f<SWZ_XOR4>(tA);
        tA += swz_f<SWZ_XOR8>(tA);
        float tB = 0.f;
        #pragma unroll
        for (int i = 0; i < 4; ++i) tB += cosv[i] * rw2[i];
        tB += dpp_f<XOR1>(tB);
        tB += dpp_f<XOR2>(tB);
        tB += swz_f<SWZ_XOR4>(tB);
        tB += swz_f<SWZ_XOR8>(tB);

        const float logits = tA + tB + rb;
        const float p = 1.f / (1.f + expf(-logits));
        const bool restart = r_re < p;

        // ---------- softmax sum: EXACT sequential relay (dpp handoff) ------
        // Global order preserved: lane r adds elements 4r..4r+3 after the
        // exact prefix from lane r-1. Rows are 16 lanes -> in-group handoff.
        float runS = 0.f;
        #pragma unroll
        for (int rr = 0; rr < 16; ++rr) {
            const float pS = dpp_shr1(runS);
            float tS = pS;
            #pragma unroll
            for (int i = 0; i < 4; ++i) tS += e[i];   // exact j-order adds
            runS = (r == rr) ? tS : runS;
        }
        const float ssum = swz_f<SWZ_BC15>(runS);

        // exact elementwise divisions (identical to baseline)
        float q[4];
        #pragma unroll
        for (int i = 0; i < 4; ++i) q[i] = e[i] / ssum;

        // ---------- CDF relay (adds only, dpp handoff) + parallel count ----
        float pfx[4];
        float runC = 0.f;
        #pragma unroll
        for (int rr = 0; rr < 16; ++rr) {
            const float pC = dpp_shr1(runC);
            if (r == rr) {
                if (rr > 0) runC = pC;
                #pragma unroll
                for (int i = 0; i < 4; ++i) {
                    runC += q[i];          // exact j-order adds
                    pfx[i] = runC;
                }
            }
        }
        int cloc = 0;
        #pragma unroll
        for (int i = 0; i < 4; ++i) cloc += (pfx[i] < r_nb) ? 1 : 0;
        int idx = cloc;   // integer add associative: tree exact
        idx += dpp_i<XOR1>(idx);
        idx += dpp_i<XOR2>(idx);
        idx += swz_i<SWZ_XOR4>(idx);
        idx += swz_i<SWZ_XOR8>(idx);
        if (idx > D_ - 1) idx = D_ - 1;

        // ---------- in-register selection (no dependent gathers) ----------
        const int owner = idx >> 2;     // lane holding element idx
        const int j     = idx & 3;
        float cand_t = tv[0];
        int   cand_i = iv[0];
        #pragma unroll
        for (int k = 1; k < 4; ++k) {
            cand_t = (j == k) ? tv[k] : cand_t;
            cand_i = (j == k) ? iv[k] : cand_i;
        }
        const float sel_t  = __shfl(cand_t, owner, 16);
        const int   sel_id = __shfl(cand_i, owner, 16);

        const int   step_n = hv ? sel_id : cur_n;
        const float step_t = hv ? sel_t  : cur_t;
        cur_n = restart ? sn : step_n;
        cur_t = restart ? st : step_t;

        if (r == 0) {
            on[l + 1] = (float)cur_n;
            ot[l + 1] = cur_t;
            op[l]     = p;
        }
    }
}

extern "C" void kernel_launch(void* const* d_in, const int* in_sizes, int n_in,
                              void* d_out, int out_size, void* d_ws, size_t ws_size,
                              hipStream_t stream) {
    const int*   nbr_ids       = (const int*)  d_in[0];
    const float* nbr_time      = (const float*)d_in[1];
    const int*   nbr_cnt       = (const int*)  d_in[2];
    const int*   start_nodes   = (const int*)  d_in[3];
    const float* start_times   = (const float*)d_in[4];
    const float* memst         = (const float*)d_in[5];
    const float* time_w        = (const float*)d_in[6];
    const float* time_b        = (const float*)d_in[7];
    const float* restart_w     = (const float*)d_in[8];
    const float* restart_b     = (const float*)d_in[9];
    const float* rand_restart  = (const float*)d_in[10];
    const float* rand_neighbor = (const float*)d_in[11];

    float* out_nodes = (float*)d_out;
    float* out_times = out_nodes + (size_t)B_ * W_ * (L_ + 1);
    float* out_probs = out_times + (size_t)B_ * W_ * (L_ + 1);

    const int threads = 256;
    const int blocks  = (NWALK * K_ + threads - 1) / threads;   // 2560
    hipLaunchKernelGGL(walk_kernel, dim3(blocks), dim3(threads), 0, stream,
                       nbr_ids, nbr_time, nbr_cnt, start_nodes, start_times,
                       memst, time_w, time_b, restart_w, restart_b,
                       rand_restart, rand_neighbor,
                       out_nodes, out_times, out_probs);
}

// Round 12
// 53.252 us; speedup vs baseline: 1.1194x; 1.1194x over previous
//
#include <hip/hip_runtime.h>
#include <math.h>

// N=100000, D=64, B=4096, W=10, L=8, M=128, T=64
constexpr int D_ = 64;
constexpr int B_ = 4096;
constexpr int W_ = 10;
constexpr int L_ = 8;
constexpr int M_ = 128;
constexpr int T_ = 64;
constexpr int NWALK = B_ * W_;   // 40960 walkers
constexpr int K_ = 8;            // lanes per walker (optimum of K-sweep 1/4/8/16)

// FINAL (R10 restore, 53.3us verified): 8 lanes per walker.
//  - All step loads issue up-front; in-register selection replaces the
//    end-of-step dependent gathers (sel_id/sel_t from resident iv/tv regs).
//  - cosf -> v_cos_f32(v_fract(x/2pi)) on the restart side only (~100x
//    margin headroom there; sampling side untouched).
//  - A/B restart-logit dots: lane-local fmac chains + commutative xor
//    butterfly (dpp quad_perm for xor1/2, ds_swizzle for xor4).
//  - S (softmax-sum) and C (CDF) folds are BYTE-IDENTICAL sequential
//    relays (dpp row_shr:1 handoff, masked hops): the reference's 21M cdf
//    compares sit at ~5e-8 margins — these chains must never be reordered.
//  - q = e/ssum via IEEE divides; expf precise: both feed the cdf compares.
__device__ __forceinline__ float dpp_shr1(float x) {
    int xi = __builtin_amdgcn_update_dpp(0, __float_as_int(x), 0x111, 0xF, 0xF, true);
    return __int_as_float(xi);
}
template <int CTRL>
__device__ __forceinline__ float dpp_f(float x) {   // quad_perm lane permute
    return __int_as_float(__builtin_amdgcn_update_dpp(0, __float_as_int(x), CTRL, 0xF, 0xF, true));
}
template <int CTRL>
__device__ __forceinline__ int dpp_i(int x) {
    return __builtin_amdgcn_update_dpp(0, x, CTRL, 0xF, 0xF, true);
}
template <int PAT>
__device__ __forceinline__ float swz_f(float x) {
    return __int_as_float(__builtin_amdgcn_ds_swizzle(__float_as_int(x), PAT));
}
template <int PAT>
__device__ __forceinline__ int swz_i(int x) {
    return __builtin_amdgcn_ds_swizzle(x, PAT);
}
constexpr int XOR1 = 0xB1;   // quad_perm [1,0,3,2]
constexpr int XOR2 = 0x4E;   // quad_perm [2,3,0,1]
constexpr float INV2PI = 0.15915494309189535f;

__global__ __launch_bounds__(256) void walk_kernel(
    const int*   __restrict__ nbr_ids,      // [N,D]
    const float* __restrict__ nbr_time,     // [N,D]
    const int*   __restrict__ nbr_cnt,      // [N]
    const int*   __restrict__ start_nodes,  // [B]
    const float* __restrict__ start_times,  // [B]
    const float* __restrict__ mem,          // [N,M]
    const float* __restrict__ time_w,       // [T]
    const float* __restrict__ time_b,       // [T]
    const float* __restrict__ restart_w,    // [M+T]
    const float* __restrict__ restart_b,    // [1]
    const float* __restrict__ rand_restart, // [L,B,W]
    const float* __restrict__ rand_neighbor,// [L,B,W]
    float* __restrict__ out_nodes,          // [B,W,L+1] (as f32)
    float* __restrict__ out_times,          // [B,W,L+1]
    float* __restrict__ out_probs)          // [B,W,L]
{
    const int tid = blockIdx.x * blockDim.x + threadIdx.x;
    const int gid = tid >> 3;          // walker id
    const int r   = tid & 7;           // lane-in-group
    if (gid >= NWALK) return;
    const int b = gid / W_;

    const int   sn = start_nodes[b];
    const float st = start_times[b];
    int   cur_n = sn;
    float cur_t = st;

    float* __restrict__ on = out_nodes + (size_t)gid * (L_ + 1);
    float* __restrict__ ot = out_times + (size_t)gid * (L_ + 1);
    float* __restrict__ op = out_probs + (size_t)gid * L_;
    if (r == 0) { on[0] = (float)sn; ot[0] = st; }

    const float rb = restart_b[0];

    // loop-invariant chunks (lane r owns mem elems 16r.., time elems 8r..)
    float wv[16];
    {
        const float4* p = reinterpret_cast<const float4*>(restart_w) + r * 4;
        float4 v0 = p[0], v1 = p[1], v2 = p[2], v3 = p[3];
        *(float4*)&wv[0] = v0; *(float4*)&wv[4] = v1;
        *(float4*)&wv[8] = v2; *(float4*)&wv[12] = v3;
    }
    float tw[8], tb[8], rw2[8];
    {
        const float4* ptw = reinterpret_cast<const float4*>(time_w + 8 * r);
        const float4* ptb = reinterpret_cast<const float4*>(time_b + 8 * r);
        const float4* prw = reinterpret_cast<const float4*>(restart_w + M_ + 8 * r);
        *(float4*)&tw[0] = ptw[0]; *(float4*)&tw[4] = ptw[1];
        *(float4*)&tb[0] = ptb[0]; *(float4*)&tb[4] = ptb[1];
        *(float4*)&rw2[0] = prw[0]; *(float4*)&rw2[4] = prw[1];
    }

    for (int l = 0; l < L_; ++l) {
        // ---------- all step loads issue up-front ----------
        const float r_re = rand_restart [(size_t)l * NWALK + gid];
        const float r_nb = rand_neighbor[(size_t)l * NWALK + gid];
        const float* __restrict__ mrow    = mem      + (size_t)cur_n * M_;
        const float* __restrict__ nts_row = nbr_time + (size_t)cur_n * D_;
        const int*   __restrict__ ids_row = nbr_ids  + (size_t)cur_n * D_;
        float mv[16];
        {
            const float4* p = reinterpret_cast<const float4*>(mrow) + r * 4;
            float4 v0 = p[0], v1 = p[1], v2 = p[2], v3 = p[3];
            *(float4*)&mv[0] = v0; *(float4*)&mv[4] = v1;
            *(float4*)&mv[8] = v2; *(float4*)&mv[12] = v3;
        }
        float tv[8];
        {
            const float4* p = reinterpret_cast<const float4*>(nts_row) + r * 2;
            float4 v0 = p[0], v1 = p[1];
            *(float4*)&tv[0] = v0; *(float4*)&tv[4] = v1;
        }
        int iv[8];
        {
            const int4* p = reinterpret_cast<const int4*>(ids_row) + r * 2;
            int4 v0 = p[0], v1 = p[1];
            *(int4*)&iv[0] = v0; *(int4*)&iv[4] = v1;
        }
        const int cnt = nbr_cnt[cur_n];

        // ---------- fast time-encoder terms (restart side only) ----------
        // cos(x) = v_cos(fract(x/2pi)); |x|<6 so the reduction is sub-ulp.
        float cosv[8];
        #pragma unroll
        for (int i = 0; i < 8; ++i) {
            const float x = cur_t * tw[i] + tb[i];
            cosv[i] = __builtin_amdgcn_cosf(__builtin_amdgcn_fractf(x * INV2PI));
        }

        float e[8];
        float lmx = -1e9f;
        #pragma unroll
        for (int i = 0; i < 8; ++i) {
            const float tj = tv[i];
            const bool  v  = (tj < cur_t) && ((8 * r + i) < cnt);
            const float s  = v ? (tj - cur_t) / 0.1f : -1e9f;   // true division
            e[i] = s;
            lmx = fmaxf(lmx, s);
        }
        lmx = fmaxf(lmx, dpp_f<XOR1>(lmx));     // xor 1 (exact permute)
        lmx = fmaxf(lmx, dpp_f<XOR2>(lmx));     // xor 2
        lmx = fmaxf(lmx, swz_f<0x101F>(lmx));   // xor 4
        const bool hv = (lmx != -1e9f);

        #pragma unroll
        for (int i = 0; i < 8; ++i) e[i] = expf(e[i] - lmx);   // EXACT (cdf path)

        // ---------- restart logit: full-lane TREE reductions ----------
        float tA = 0.f;
        #pragma unroll
        for (int i = 0; i < 16; ++i) tA += mv[i] * wv[i];   // lane-local fmac chain
        tA += dpp_f<XOR1>(tA);
        tA += dpp_f<XOR2>(tA);
        tA += swz_f<0x101F>(tA);
        float tB = 0.f;
        #pragma unroll
        for (int i = 0; i < 8; ++i) tB += cosv[i] * rw2[i];
        tB += dpp_f<XOR1>(tB);
        tB += dpp_f<XOR2>(tB);
        tB += swz_f<0x101F>(tB);

        const float logits = tA + tB + rb;
        const float p = 1.f / (1.f + expf(-logits));
        const bool restart = r_re < p;

        // ---------- softmax sum: EXACT sequential relay (dpp handoff) ------
        float runS = 0.f;
        #pragma unroll
        for (int rr = 0; rr < 8; ++rr) {
            const float pS = dpp_shr1(runS);
            float tS = pS;
            #pragma unroll
            for (int i = 0; i < 8; ++i) tS += e[i];   // exact j-order adds
            runS = (r == rr) ? tS : runS;
        }
        const float ssum = swz_f<0x00F8>(runS);

        // exact elementwise divisions (identical to baseline)
        float q[8];
        #pragma unroll
        for (int i = 0; i < 8; ++i) q[i] = e[i] / ssum;

        // ---------- CDF relay (adds only, dpp handoff) + parallel count ----
        float pfx[8];
        float runC = 0.f;
        #pragma unroll
        for (int rr = 0; rr < 8; ++rr) {
            const float pC = dpp_shr1(runC);
            if (r == rr) {
                if (rr > 0) runC = pC;
                #pragma unroll
                for (int i = 0; i < 8; ++i) {
                    runC += q[i];          // exact j-order adds
                    pfx[i] = runC;
                }
            }
        }
        int cloc = 0;
        #pragma unroll
        for (int i = 0; i < 8; ++i) cloc += (pfx[i] < r_nb) ? 1 : 0;
        int idx = cloc;   // integer add associative: tree exact
        idx += dpp_i<XOR1>(idx);
        idx += dpp_i<XOR2>(idx);
        idx += swz_i<0x101F>(idx);
        if (idx > D_ - 1) idx = D_ - 1;

        // ---------- in-register selection (no dependent gathers) ----------
        const int owner = idx >> 3;
        const int j     = idx & 7;
        float cand_t = tv[0];
        int   cand_i = iv[0];
        #pragma unroll
        for (int k = 1; k < 8; ++k) {
            cand_t = (j == k) ? tv[k] : cand_t;
            cand_i = (j == k) ? iv[k] : cand_i;
        }
        const float sel_t  = __shfl(cand_t, owner, 8);
        const int   sel_id = __shfl(cand_i, owner, 8);

        const int   step_n = hv ? sel_id : cur_n;
        const float step_t = hv ? sel_t  : cur_t;
        cur_n = restart ? sn : step_n;
        cur_t = restart ? st : step_t;

        if (r == 0) {
            on[l + 1] = (float)cur_n;
            ot[l + 1] = cur_t;
            op[l]     = p;
        }
    }
}

extern "C" void kernel_launch(void* const* d_in, const int* in_sizes, int n_in,
                              void* d_out, int out_size, void* d_ws, size_t ws_size,
                              hipStream_t stream) {
    const int*   nbr_ids       = (const int*)  d_in[0];
    const float* nbr_time      = (const float*)d_in[1];
    const int*   nbr_cnt       = (const int*)  d_in[2];
    const int*   start_nodes   = (const int*)  d_in[3];
    const float* start_times   = (const float*)d_in[4];
    const float* memst         = (const float*)d_in[5];
    const float* time_w        = (const float*)d_in[6];
    const float* time_b        = (const float*)d_in[7];
    const float* restart_w     = (const float*)d_in[8];
    const float* restart_b     = (const float*)d_in[9];
    const float* rand_restart  = (const float*)d_in[10];
    const float* rand_neighbor = (const float*)d_in[11];

    float* out_nodes = (float*)d_out;
    float* out_times = out_nodes + (size_t)B_ * W_ * (L_ + 1);
    float* out_probs = out_times + (size_t)B_ * W_ * (L_ + 1);

    const int threads = 256;
    const int blocks  = (NWALK * K_ + threads - 1) / threads;   // 1280
    hipLaunchKernelGGL(walk_kernel, dim3(blocks), dim3(threads), 0, stream,
                       nbr_ids, nbr_time, nbr_cnt, start_nodes, start_times,
                       memst, time_w, time_b, restart_w, restart_b,
                       rand_restart, rand_neighbor,
                       out_nodes, out_times, out_probs);
}